// Round 6
// baseline (384.122 us; speedup 1.0000x reference)
//
#include <hip/hip_runtime.h>
#include <hip/hip_bf16.h>

using bf16 = __hip_bfloat16;

typedef __attribute__((ext_vector_type(8))) short short8;   // 8 x bf16 (4 VGPRs)
typedef __attribute__((ext_vector_type(4))) float f32x4;    // MFMA C/D

// MaskedMSA: B=4, S=2048, E=1024, HIDDEN=1024, HEADS=16
// Reference reshape mixes seq/hidden: with t=16u+r (u<128, r<16):
//   q[b,h,t,e] = qkv[b, 128h+u, 192r +   0 + e]
//   k[b,h,t,e] = qkv[b, 128h+u, 192r +  64 + e]
//   v[b,h,t,e] = qkv[b, 128h+u, 192r + 128 + e]
// Output: sa[b,h,t,e] -> out row 128h+u, col 64r+e. Causal mask on permuted t.
// Q columns of W_qkv/b_qkv are pre-scaled by scale*log2(e) so QK^T scores
// arrive in exp2-domain.

#define CEXP 0.03188127742677263f  // (2*1024)^-0.5 * log2(e)

__device__ __forceinline__ unsigned short f2bf(float v) {
  bf16 h = __float2bfloat16(v);
  return *(unsigned short*)&h;
}

// async global->LDS, 16B per lane; LDS dest = wave-uniform base + lane*16.
__device__ __forceinline__ void gload_lds16(const void* g, void* lds) {
  __builtin_amdgcn_global_load_lds(
      (const __attribute__((address_space(1))) unsigned int*)(g),
      (__attribute__((address_space(3))) unsigned int*)(lds), 16, 0, 0);
}

// ---- dtype detect: flag=1 if fp32 I/O, flag=0 if bf16 I/O.
__global__ void detect_kernel(const unsigned int* __restrict__ x, int* __restrict__ flag) {
  unsigned int w = x[threadIdx.x];
  unsigned int e = (w >> 7) & 0xFF;
  bool inband = (e >= 96 && e <= 133);
  unsigned long long m = __ballot(inband);
  if (threadIdx.x == 0) flag[0] = (__popcll(m) >= 48) ? 0 : 1;
}

// ---- convert n8*8 elements to bf16 (copy if already bf16)
__global__ __launch_bounds__(256) void convert_kernel(
    const void* __restrict__ src, bf16* __restrict__ dst, int n8,
    const int* __restrict__ flag) {
  int i = blockIdx.x * 256 + threadIdx.x;
  if (i >= n8) return;
  uint4 outv;
  if (*flag) {
    const float4* s = (const float4*)src + (size_t)i * 2;
    float4 a = s[0], b = s[1];
    outv.x = f2bf(a.x) | ((unsigned)f2bf(a.y) << 16);
    outv.y = f2bf(a.z) | ((unsigned)f2bf(a.w) << 16);
    outv.z = f2bf(b.x) | ((unsigned)f2bf(b.y) << 16);
    outv.w = f2bf(b.z) | ((unsigned)f2bf(b.w) << 16);
  } else {
    outv = ((const uint4*)src)[i];
  }
  ((uint4*)dst)[i] = outv;
}

// ---- b_qkv convert with Q-column pre-scale (cols with (i%192)<64)
__global__ void convert_bias_qkv(const void* __restrict__ src, bf16* __restrict__ dst,
                                 const int* __restrict__ flag) {
  int i = blockIdx.x * 256 + threadIdx.x;
  if (i >= 3072) return;
  float v = (*flag) ? ((const float*)src)[i]
                    : __bfloat162float(((const bf16*)src)[i]);
  if ((i % 192) < 64) v *= CEXP;
  dst[i] = __float2bfloat16(v);
}

// ---- transpose src[R][C] -> dst[C][R] (bf16 out); qscale: scale rows n with
// (n%192)<64 by CEXP (used for W_qkv -> Q columns in exp2 domain).
__global__ __launch_bounds__(256) void transpose_bf16(
    const void* __restrict__ src, bf16* __restrict__ dst, int R, int Cc,
    const int* __restrict__ flag, int qscale) {
  __shared__ float tile[32][33];
  const int c0 = blockIdx.x * 32, r0 = blockIdx.y * 32;
  const int tx = threadIdx.x & 31, ty = threadIdx.x >> 5;  // 32 x 8
  const bool f32 = (*flag != 0);
#pragma unroll
  for (int it = 0; it < 4; ++it) {
    int r = ty + it * 8;
    float v;
    if (f32) v = ((const float*)src)[(size_t)(r0 + r) * Cc + c0 + tx];
    else     v = __bfloat162float(((const bf16*)src)[(size_t)(r0 + r) * Cc + c0 + tx]);
    tile[r][tx] = v;
  }
  __syncthreads();
#pragma unroll
  for (int it = 0; it < 4; ++it) {
    int r = ty + it * 8;   // dst row n = c0 + r
    float vv = tile[tx][r];
    if (qscale && (((c0 + r) % 192) < 64)) vv *= CEXP;
    dst[(size_t)(c0 + r) * R + r0 + tx] = __float2bfloat16(vv);
  }
}

// ---------------- MFMA GEMM (m97 pattern): C[M,N] = A[M,K] @ BT[N,K]^T + bias
__global__ __launch_bounds__(256) void gemm_mfma(
    const bf16* __restrict__ A, const bf16* __restrict__ BT,
    const bf16* __restrict__ bias, void* __restrict__ C,
    int M, int N, int K, int store_mode, const int* __restrict__ flag)
{
  __shared__ alignas(16) unsigned short As[128 * 32];  // [m][k] contiguous
  __shared__ alignas(16) unsigned short Bs[128 * 32];  // [n][k] contiguous
  const bool store_f32 = store_mode && (*flag != 0);
  const int tid = threadIdx.x;
  const int wave = tid >> 6, lane = tid & 63;
  const int l15 = lane & 15, l4 = lane >> 4;
  const int m0 = blockIdx.y * 128, n0 = blockIdx.x * 128;
  const int wm = (wave & 1) * 64, wn = (wave >> 1) * 64;

  const int srow = wave * 32 + (lane >> 2);
  const int skv = (lane & 3) * 8;
  const bf16* ga = A + (size_t)(m0 + srow) * K + skv;
  const bf16* gb = BT + (size_t)(n0 + srow) * K + skv;
  unsigned short* la = As + (wave * 32) * 32;
  unsigned short* lb = Bs + (wave * 32) * 32;

  f32x4 acc[4][4] = {};

  for (int k0 = 0; k0 < K; k0 += 32) {
    __syncthreads();
    gload_lds16(ga, la);
    gload_lds16(ga + (size_t)16 * K, la + 16 * 32);
    gload_lds16(gb, lb);
    gload_lds16(gb + (size_t)16 * K, lb + 16 * 32);
    ga += 32; gb += 32;
    __syncthreads();

    short8 af[4], bfr[4];
#pragma unroll
    for (int i = 0; i < 4; ++i) {
      af[i]  = *(const short8*)(As + (wm + i * 16 + l15) * 32 + l4 * 8);
      bfr[i] = *(const short8*)(Bs + (wn + i * 16 + l15) * 32 + l4 * 8);
    }
#pragma unroll
    for (int i = 0; i < 4; ++i)
#pragma unroll
      for (int j = 0; j < 4; ++j)
        acc[i][j] = __builtin_amdgcn_mfma_f32_16x16x32_bf16(af[i], bfr[j], acc[i][j], 0, 0, 0);
  }

#pragma unroll
  for (int j = 0; j < 4; ++j) {
    const int n = n0 + wn + j * 16 + l15;
    const float bv = __bfloat162float(bias[n]);
#pragma unroll
    for (int i = 0; i < 4; ++i) {
#pragma unroll
      for (int r = 0; r < 4; ++r) {
        const int mrow = m0 + wm + i * 16 + l4 * 4 + r;
        const float v = acc[i][j][r] + bv;
        if (store_f32) ((float*)C)[(size_t)mrow * N + n] = v;
        else           ((bf16*)C)[(size_t)mrow * N + n] = __float2bfloat16(v);
      }
    }
  }
}

// ---------------- MFMA flash attention, uniform-work pairing.
// grid (64 bh, 16 y); block handles q-tiles y and 31-y => 33 iters/block, all
// 1024 blocks co-resident (4/CU), no occupancy decay. Scores arrive in
// exp2-domain (pre-scaled Q). Row-sum l folded into PV via ones-column
// accumulator. V software-pipelined in registers. 2 barriers/iter.
__global__ __launch_bounds__(256, 4) void attn_mfma(const bf16* __restrict__ qkv,
                                                    bf16* __restrict__ sa)
{
  __shared__ short Vt[64 * 72];        // [d][key], stride 72
  __shared__ short Ps[4 * 16 * 76];    // per-wave [q_local][key], stride 76 (2-way free)
  const int tid = threadIdx.x;
  const int bh = blockIdx.x;
  const int y = blockIdx.y;
  const size_t base = (size_t)bh * 393216;  // (bh*128) * 3072
  const int wave = tid >> 6;
  const int lane = tid & 63;
  const int l15 = lane & 15;
  const int l4 = lane >> 4;
  const unsigned short* qk = (const unsigned short*)qkv;

  // V pipeline: this thread owns key=tid&63, d-vectors dv0 and dv0+4
  const int key = tid & 63;
  const int dv0 = tid >> 6;
  const unsigned short* vbase =
      qk + base + (size_t)(key >> 4) * 3072 + (key & 15) * 192 + 128;
  short* psw = Ps + wave * (16 * 76);

  short8 ones_b;   // B-frag: V ones-column at n==0 -> row-sum accumulator
#pragma unroll
  for (int j = 0; j < 8; ++j) ones_b[j] = (l15 == 0) ? (short)0x3F80 : (short)0;

  for (int ph = 0; ph < 2; ++ph) {
    const int qt = ph ? (31 - y) : y;

    short8 qf0, qf1;
    {
      const unsigned short* p = qk + base + (size_t)(qt * 4 + wave) * 3072 + l15 * 192 + l4 * 8;
      qf0 = *(const short8*)p;
      qf1 = *(const short8*)(p + 32);
    }
    short8 vn0 = *(const short8*)(vbase + dv0 * 8);   // kt=0 prefetch
    short8 vn1 = *(const short8*)(vbase + (dv0 + 4) * 8);

    f32x4 o[4] = {};
    f32x4 ol = {};                      // row-sum accumulator (col 0 lanes)
    float mrow[4];
#pragma unroll
    for (int r = 0; r < 4; ++r) mrow[r] = -__builtin_inff();

    for (int kt = 0; kt <= qt; ++kt) {
      __syncthreads();                  // prior PV reads of Vt done
      {
#pragma unroll
        for (int jj = 0; jj < 8; ++jj) {
          Vt[(dv0 * 8 + jj) * 72 + key] = vn0[jj];
          Vt[((dv0 + 4) * 8 + jj) * 72 + key] = vn1[jj];
        }
      }
      if (kt < qt) {                    // prefetch next V during this iter
        const unsigned short* pv = vbase + (size_t)(kt + 1) * 12288;  // 4*3072
        vn0 = *(const short8*)(pv + dv0 * 8);
        vn1 = *(const short8*)(pv + (dv0 + 4) * 8);
      }
      __syncthreads();                  // Vt ready

      f32x4 sc[4];
#pragma unroll
      for (int jn = 0; jn < 4; ++jn) {
        const unsigned short* pk =
            qk + base + (size_t)(kt * 4 + jn) * 3072 + l15 * 192 + 64 + l4 * 8;
        short8 k0 = *(const short8*)pk;
        short8 k1 = *(const short8*)(pk + 32);
        f32x4 c = {};
        c = __builtin_amdgcn_mfma_f32_16x16x32_bf16(qf0, k0, c, 0, 0, 0);
        c = __builtin_amdgcn_mfma_f32_16x16x32_bf16(qf1, k1, c, 0, 0, 0);
        sc[jn] = c;
      }

      if (kt == qt) {                   // wave-uniform diag branch
#pragma unroll
        for (int r = 0; r < 4; ++r)
#pragma unroll
          for (int jn = 0; jn < 4; ++jn)
            if (jn * 16 + l15 > wave * 16 + l4 * 4 + r) sc[jn][r] = -__builtin_inff();
      }

#pragma unroll
      for (int r = 0; r < 4; ++r) {
        float mx = fmaxf(fmaxf(sc[0][r], sc[1][r]), fmaxf(sc[2][r], sc[3][r]));
        mx = fmaxf(mx, __shfl_xor(mx, 1, 64));
        mx = fmaxf(mx, __shfl_xor(mx, 2, 64));
        mx = fmaxf(mx, __shfl_xor(mx, 4, 64));
        mx = fmaxf(mx, __shfl_xor(mx, 8, 64));
        const float m_new = fmaxf(mrow[r], mx);
        const float alpha = __builtin_amdgcn_exp2f(mrow[r] - m_new);
        mrow[r] = m_new;
#pragma unroll
        for (int jn = 0; jn < 4; ++jn) {
          float p = __builtin_amdgcn_exp2f(sc[jn][r] - m_new);
          psw[(l4 * 4 + r) * 76 + jn * 16 + l15] = (short)f2bf(p);
          o[jn][r] *= alpha;
        }
        ol[r] *= alpha;
      }

      // P: C layout -> A layout (wave-private LDS; same-wave DS order, no barrier)
      short8 pf0 = *(const short8*)(psw + l15 * 76 + l4 * 8);
      short8 pf1 = *(const short8*)(psw + l15 * 76 + 32 + l4 * 8);

#pragma unroll
      for (int jn = 0; jn < 4; ++jn) {
        const short* pvt = Vt + (jn * 16 + l15) * 72 + l4 * 8;
        short8 v0 = *(const short8*)pvt;
        short8 v1 = *(const short8*)(pvt + 32);
        o[jn] = __builtin_amdgcn_mfma_f32_16x16x32_bf16(pf0, v0, o[jn], 0, 0, 0);
        o[jn] = __builtin_amdgcn_mfma_f32_16x16x32_bf16(pf1, v1, o[jn], 0, 0, 0);
      }
      ol = __builtin_amdgcn_mfma_f32_16x16x32_bf16(pf0, ones_b, ol, 0, 0, 0);
      ol = __builtin_amdgcn_mfma_f32_16x16x32_bf16(pf1, ones_b, ol, 0, 0, 0);
    }

    unsigned short* so = (unsigned short*)sa + (size_t)(bh * 128 + qt * 4 + wave) * 1024;
#pragma unroll
    for (int r = 0; r < 4; ++r) {
      const float lsum = __shfl(ol[r], lane & 48, 64);  // col-0 lane of this row group
      const float inv = 1.0f / lsum;
      const int qloc = l4 * 4 + r;
#pragma unroll
      for (int jn = 0; jn < 4; ++jn)
        so[qloc * 64 + jn * 16 + l15] = f2bf(o[jn][r] * inv);
    }
  }
}

extern "C" void kernel_launch(void* const* d_in, const int* in_sizes, int n_in,
                              void* d_out, int out_size, void* d_ws, size_t ws_size,
                              hipStream_t stream)
{
  const void* x_raw    = d_in[0];  // [4,2048,1024]
  const void* Wqkv_raw = d_in[1];  // [1024,3072]
  const void* bqkv_raw = d_in[2];  // [3072]
  const void* Wout_raw = d_in[3];  // [1024,1024]
  const void* bout_raw = d_in[4];  // [1024]

  char* ws = (char*)d_ws;
  int*  flag   = (int*)ws;                                  //   256 B
  bf16* xb     = (bf16*)(ws + 256);                         //  16 MiB (8192*1024)
  bf16* wqkvT  = xb + (size_t)8192 * 1024;                  //   6 MiB (3072*1024, [N][K])
  bf16* bqkvb  = wqkvT + (size_t)3072 * 1024;               //   6 KiB
  bf16* woutT  = bqkvb + 4096;                              //   2 MiB (1024*1024, [N][K])
  bf16* boutb  = woutT + (size_t)1024 * 1024;               //   2 KiB
  bf16* qkv    = boutb + 4096;                              //  48 MiB (8192*3072)
  bf16* sa     = qkv + (size_t)8192 * 3072;                 //  16 MiB (8192*1024)

  detect_kernel<<<1, 64, 0, stream>>>((const unsigned int*)x_raw, flag);

  convert_kernel<<<(8192 * 1024 / 8 + 255) / 256, 256, 0, stream>>>(x_raw, xb, 8192 * 1024 / 8, flag);
  convert_bias_qkv<<<12, 256, 0, stream>>>(bqkv_raw, bqkvb, flag);
  convert_kernel<<<1, 256, 0, stream>>>(bout_raw, boutb, 1024 / 8, flag);
  transpose_bf16<<<dim3(3072 / 32, 1024 / 32), 256, 0, stream>>>(Wqkv_raw, wqkvT, 1024, 3072, flag, 1);
  transpose_bf16<<<dim3(1024 / 32, 1024 / 32), 256, 0, stream>>>(Wout_raw, woutT, 1024, 1024, flag, 0);

  // 1) qkv = x @ W_qkv + b_qkv   (M=8192, N=3072, K=1024); Q cols pre-scaled
  gemm_mfma<<<dim3(3072 / 128, 8192 / 128), 256, 0, stream>>>(
      xb, wqkvT, bqkvb, qkv, 8192, 3072, 1024, 0, flag);
  // 2) MFMA flash attention (uniform-work pairing: y and 31-y)
  attn_mfma<<<dim3(64, 16), 256, 0, stream>>>(qkv, sa);
  // 3) out = sa @ W_out + b_out  (M=8192, N=1024, K=1024)
  gemm_mfma<<<dim3(1024 / 128, 8192 / 128), 256, 0, stream>>>(
      sa, woutT, boutb, d_out, 8192, 1024, 1024, 1, flag);
}

// Round 7
// 364.410 us; speedup vs baseline: 1.0541x; 1.0541x over previous
//
#include <hip/hip_runtime.h>
#include <hip/hip_bf16.h>

using bf16 = __hip_bfloat16;

typedef __attribute__((ext_vector_type(8))) short short8;   // 8 x bf16 (4 VGPRs)
typedef __attribute__((ext_vector_type(4))) float f32x4;    // MFMA C/D

// MaskedMSA: B=4, S=2048, E=1024, HIDDEN=1024, HEADS=16
// Reference reshape mixes seq/hidden: with t=16u+r (u<128, r<16):
//   q[b,h,t,e] = qkv[b, 128h+u, 192r +   0 + e]
//   k[b,h,t,e] = qkv[b, 128h+u, 192r +  64 + e]
//   v[b,h,t,e] = qkv[b, 128h+u, 192r + 128 + e]
// Output: sa[b,h,t,e] -> out row 128h+u, col 64r+e. Causal mask on permuted t.
// Q columns of W_qkv/b_qkv are pre-scaled by scale*log2(e): exp2-domain scores.
// Attention computes S^T = mfma(K,Q) and O^T = mfma(Vt,P): softmax is
// lane-local (lane = q row), P transform is 4x ds_write_b64 + 2x ds_read_b128.

#define CEXP 0.03188127742677263f  // (2*1024)^-0.5 * log2(e)

__device__ __forceinline__ unsigned short f2bf(float v) {
  bf16 h = __float2bfloat16(v);
  return *(unsigned short*)&h;
}
__device__ __forceinline__ unsigned int pack2bf(float a, float b) {
  return (unsigned int)f2bf(a) | ((unsigned int)f2bf(b) << 16);
}

// async global->LDS, 16B per lane; LDS dest = wave-uniform base + lane*16.
__device__ __forceinline__ void gload_lds16(const void* g, void* lds) {
  __builtin_amdgcn_global_load_lds(
      (const __attribute__((address_space(1))) unsigned int*)(g),
      (__attribute__((address_space(3))) unsigned int*)(lds), 16, 0, 0);
}

// ---- dtype detect: flag=1 if fp32 I/O, flag=0 if bf16 I/O.
__global__ void detect_kernel(const unsigned int* __restrict__ x, int* __restrict__ flag) {
  unsigned int w = x[threadIdx.x];
  unsigned int e = (w >> 7) & 0xFF;
  bool inband = (e >= 96 && e <= 133);
  unsigned long long m = __ballot(inband);
  if (threadIdx.x == 0) flag[0] = (__popcll(m) >= 48) ? 0 : 1;
}

// ---- convert n8*8 elements to bf16 (copy if already bf16)
__global__ __launch_bounds__(256) void convert_kernel(
    const void* __restrict__ src, bf16* __restrict__ dst, int n8,
    const int* __restrict__ flag) {
  int i = blockIdx.x * 256 + threadIdx.x;
  if (i >= n8) return;
  uint4 outv;
  if (*flag) {
    const float4* s = (const float4*)src + (size_t)i * 2;
    float4 a = s[0], b = s[1];
    outv.x = pack2bf(a.x, a.y);
    outv.y = pack2bf(a.z, a.w);
    outv.z = pack2bf(b.x, b.y);
    outv.w = pack2bf(b.z, b.w);
  } else {
    outv = ((const uint4*)src)[i];
  }
  ((uint4*)dst)[i] = outv;
}

// ---- b_qkv convert with Q-column pre-scale (cols with (i%192)<64)
__global__ void convert_bias_qkv(const void* __restrict__ src, bf16* __restrict__ dst,
                                 const int* __restrict__ flag) {
  int i = blockIdx.x * 256 + threadIdx.x;
  if (i >= 3072) return;
  float v = (*flag) ? ((const float*)src)[i]
                    : __bfloat162float(((const bf16*)src)[i]);
  if ((i % 192) < 64) v *= CEXP;
  dst[i] = __float2bfloat16(v);
}

// ---- transpose src[R][C] -> dst[C][R] (bf16 out); qscale: scale rows n with
// (n%192)<64 by CEXP (W_qkv Q columns -> exp2 domain).
__global__ __launch_bounds__(256) void transpose_bf16(
    const void* __restrict__ src, bf16* __restrict__ dst, int R, int Cc,
    const int* __restrict__ flag, int qscale) {
  __shared__ float tile[32][33];
  const int c0 = blockIdx.x * 32, r0 = blockIdx.y * 32;
  const int tx = threadIdx.x & 31, ty = threadIdx.x >> 5;  // 32 x 8
  const bool f32 = (*flag != 0);
#pragma unroll
  for (int it = 0; it < 4; ++it) {
    int r = ty + it * 8;
    float v;
    if (f32) v = ((const float*)src)[(size_t)(r0 + r) * Cc + c0 + tx];
    else     v = __bfloat162float(((const bf16*)src)[(size_t)(r0 + r) * Cc + c0 + tx]);
    tile[r][tx] = v;
  }
  __syncthreads();
#pragma unroll
  for (int it = 0; it < 4; ++it) {
    int r = ty + it * 8;   // dst row n = c0 + r
    float vv = tile[tx][r];
    if (qscale && (((c0 + r) % 192) < 64)) vv *= CEXP;
    dst[(size_t)(c0 + r) * R + r0 + tx] = __float2bfloat16(vv);
  }
}

// ---------------- MFMA GEMM (m97 pattern): C[M,N] = A[M,K] @ BT[N,K]^T + bias
__global__ __launch_bounds__(256) void gemm_mfma(
    const bf16* __restrict__ A, const bf16* __restrict__ BT,
    const bf16* __restrict__ bias, void* __restrict__ C,
    int M, int N, int K, int store_mode, const int* __restrict__ flag)
{
  __shared__ alignas(16) unsigned short As[128 * 32];  // [m][k] contiguous
  __shared__ alignas(16) unsigned short Bs[128 * 32];  // [n][k] contiguous
  const bool store_f32 = store_mode && (*flag != 0);
  const int tid = threadIdx.x;
  const int wave = tid >> 6, lane = tid & 63;
  const int l15 = lane & 15, l4 = lane >> 4;
  const int m0 = blockIdx.y * 128, n0 = blockIdx.x * 128;
  const int wm = (wave & 1) * 64, wn = (wave >> 1) * 64;

  const int srow = wave * 32 + (lane >> 2);
  const int skv = (lane & 3) * 8;
  const bf16* ga = A + (size_t)(m0 + srow) * K + skv;
  const bf16* gb = BT + (size_t)(n0 + srow) * K + skv;
  unsigned short* la = As + (wave * 32) * 32;
  unsigned short* lb = Bs + (wave * 32) * 32;

  f32x4 acc[4][4] = {};

  for (int k0 = 0; k0 < K; k0 += 32) {
    __syncthreads();
    gload_lds16(ga, la);
    gload_lds16(ga + (size_t)16 * K, la + 16 * 32);
    gload_lds16(gb, lb);
    gload_lds16(gb + (size_t)16 * K, lb + 16 * 32);
    ga += 32; gb += 32;
    __syncthreads();

    short8 af[4], bfr[4];
#pragma unroll
    for (int i = 0; i < 4; ++i) {
      af[i]  = *(const short8*)(As + (wm + i * 16 + l15) * 32 + l4 * 8);
      bfr[i] = *(const short8*)(Bs + (wn + i * 16 + l15) * 32 + l4 * 8);
    }
#pragma unroll
    for (int i = 0; i < 4; ++i)
#pragma unroll
      for (int j = 0; j < 4; ++j)
        acc[i][j] = __builtin_amdgcn_mfma_f32_16x16x32_bf16(af[i], bfr[j], acc[i][j], 0, 0, 0);
  }

#pragma unroll
  for (int j = 0; j < 4; ++j) {
    const int n = n0 + wn + j * 16 + l15;
    const float bv = __bfloat162float(bias[n]);
#pragma unroll
    for (int i = 0; i < 4; ++i) {
#pragma unroll
      for (int r = 0; r < 4; ++r) {
        const int mrow = m0 + wm + i * 16 + l4 * 4 + r;
        const float v = acc[i][j][r] + bv;
        if (store_f32) ((float*)C)[(size_t)mrow * N + n] = v;
        else           ((bf16*)C)[(size_t)mrow * N + n] = __float2bfloat16(v);
      }
    }
  }
}

// ---------------- MFMA flash attention, transposed (S^T / O^T) formulation.
// grid (64 bh, 16 y); block handles q-tiles y and 31-y (33 iters, uniform).
// Per wave: 16 q rows (q = l15); S^T = mfma(K, Q) -> lane-local softmax;
// P -> LDS via 4x b64 writes; O^T = mfma(Vt, P). V staged [d][key] in LDS.
__global__ __launch_bounds__(256, 4) void attn_mfma(const bf16* __restrict__ qkv,
                                                    bf16* __restrict__ sa)
{
  __shared__ alignas(16) short Vt[64 * 72];       // [d][key], stride 72 (144B, 16B-mult)
  __shared__ alignas(16) short Ps[4][16 * 72];    // per-wave [q][key], stride 72
  const int tid = threadIdx.x;
  const int bh = blockIdx.x;
  const int y = blockIdx.y;
  const size_t base = (size_t)bh * 393216;        // (bh*128) * 3072
  const int wave = tid >> 6;
  const int lane = tid & 63;
  const int l15 = lane & 15;
  const int l4 = lane >> 4;
  const unsigned short* qk = (const unsigned short*)qkv;

  // V staging ownership: this thread owns key=tid&63, d-vectors dv0 and dv0+4
  const int key = tid & 63;
  const int dv0 = tid >> 6;
  const unsigned short* vbase =
      qk + base + (size_t)(key >> 4) * 3072 + (key & 15) * 192 + 128;
  short* psw = &Ps[wave][0];

  for (int ph = 0; ph < 2; ++ph) {
    const int qt = ph ? (31 - y) : y;

    // Q B-frag: B[n=q(l15)][k=d(l4*8+j)]
    const unsigned short* pq = qk + base + (size_t)(qt * 4 + wave) * 3072 + l15 * 192 + l4 * 8;
    short8 qf0 = *(const short8*)pq;
    short8 qf1 = *(const short8*)(pq + 32);
    // V regs for kt=0
    short8 vn0 = *(const short8*)(vbase + dv0 * 8);
    short8 vn1 = *(const short8*)(vbase + (dv0 + 4) * 8);

    f32x4 o[4] = {};                 // O^T: col=q(l15), row=d(16jn+4l4+r)
    float mloc = -__builtin_inff();  // per-lane = per-q-row
    float lsum = 0.f;

    for (int kt = 0; kt <= qt; ++kt) {
      // K A-frags for this kt: A[m=key(l15)][k=d] -- issue early; the barrier
      // drain absorbs their latency alongside the V prefetch.
      short8 kf0[4], kf1[4];
#pragma unroll
      for (int t = 0; t < 4; ++t) {
        const unsigned short* pk =
            qk + base + (size_t)(kt * 4 + t) * 3072 + l15 * 192 + 64 + l4 * 8;
        kf0[t] = *(const short8*)pk;
        kf1[t] = *(const short8*)(pk + 32);
      }
      // prefetch next V tile
      short8 vx0 = vn0, vx1 = vn1;
      if (kt < qt) {
        const unsigned short* pv = vbase + (size_t)(kt + 1) * 12288;  // 4*3072
        vn0 = *(const short8*)(pv + dv0 * 8);
        vn1 = *(const short8*)(pv + (dv0 + 4) * 8);
      }
      __syncthreads();               // prior PV reads of Vt done (drains loads)
#pragma unroll
      for (int jj = 0; jj < 8; ++jj) {
        Vt[(dv0 * 8 + jj) * 72 + key] = vx0[jj];
        Vt[((dv0 + 4) * 8 + jj) * 72 + key] = vx1[jj];
      }
      __syncthreads();               // Vt ready (clean barrier: no pending vmem)

      // ---- S^T = K . Q^T : col=q(l15), row=key_local(16t+4l4+r)
      f32x4 sc[4];
#pragma unroll
      for (int t = 0; t < 4; ++t) {
        f32x4 c = {};
        c = __builtin_amdgcn_mfma_f32_16x16x32_bf16(kf0[t], qf0, c, 0, 0, 0);
        c = __builtin_amdgcn_mfma_f32_16x16x32_bf16(kf1[t], qf1, c, 0, 0, 0);
        sc[t] = c;
      }

      if (kt == qt) {                // wave-uniform diag branch
        const int qloc = wave * 16 + l15;
#pragma unroll
        for (int t = 0; t < 4; ++t)
#pragma unroll
          for (int r = 0; r < 4; ++r)
            if (16 * t + 4 * l4 + r > qloc) sc[t][r] = -__builtin_inff();
      }

      // ---- lane-local online softmax over this lane's 16 keys + cross-l4 reduce
      float mx = -__builtin_inff();
#pragma unroll
      for (int t = 0; t < 4; ++t)
#pragma unroll
        for (int r = 0; r < 4; ++r) mx = fmaxf(mx, sc[t][r]);
      mx = fmaxf(mx, __shfl_xor(mx, 16, 64));
      mx = fmaxf(mx, __shfl_xor(mx, 32, 64));
      const float m_new = fmaxf(mloc, mx);
      const float alpha = __builtin_amdgcn_exp2f(mloc - m_new);
      mloc = m_new;
      float s = 0.f;
      unsigned int pk2[4][2];
#pragma unroll
      for (int t = 0; t < 4; ++t) {
        float p0 = __builtin_amdgcn_exp2f(sc[t][0] - m_new);
        float p1 = __builtin_amdgcn_exp2f(sc[t][1] - m_new);
        float p2 = __builtin_amdgcn_exp2f(sc[t][2] - m_new);
        float p3 = __builtin_amdgcn_exp2f(sc[t][3] - m_new);
        s += (p0 + p1) + (p2 + p3);
        pk2[t][0] = pack2bf(p0, p1);
        pk2[t][1] = pack2bf(p2, p3);
      }
      s += __shfl_xor(s, 16, 64);
      s += __shfl_xor(s, 32, 64);
      lsum = lsum * alpha + s;
#pragma unroll
      for (int jn = 0; jn < 4; ++jn)
#pragma unroll
        for (int r = 0; r < 4; ++r) o[jn][r] *= alpha;

      // ---- P -> LDS [q][key]: lane writes its 4 consecutive keys per tile (b64)
#pragma unroll
      for (int t = 0; t < 4; ++t) {
        uint2 w; w.x = pk2[t][0]; w.y = pk2[t][1];
        *(uint2*)(psw + l15 * 72 + 16 * t + 4 * l4) = w;
      }
      // B-frag read (same wave, program-ordered: no barrier needed)
      short8 pf0 = *(const short8*)(psw + l15 * 72 + l4 * 8);
      short8 pf1 = *(const short8*)(psw + l15 * 72 + 32 + l4 * 8);

      // ---- O^T += V^T . P^T : A[m=d][k=key] from Vt, B[n=q][k=key] = P
#pragma unroll
      for (int jn = 0; jn < 4; ++jn) {
        const short* pvt = Vt + (jn * 16 + l15) * 72 + l4 * 8;
        short8 v0 = *(const short8*)pvt;
        short8 v1 = *(const short8*)(pvt + 32);
        o[jn] = __builtin_amdgcn_mfma_f32_16x16x32_bf16(v0, pf0, o[jn], 0, 0, 0);
        o[jn] = __builtin_amdgcn_mfma_f32_16x16x32_bf16(v1, pf1, o[jn], 0, 0, 0);
      }
    }

    // ---- epilogue: lane owns q row (qt*4+wave, inner l15); d = 16jn+4l4+r
    const float inv = 1.0f / lsum;
    unsigned short* so = (unsigned short*)sa + (size_t)(bh * 128 + qt * 4 + wave) * 1024;
#pragma unroll
    for (int jn = 0; jn < 4; ++jn) {
      uint2 w;
      w.x = pack2bf(o[jn][0] * inv, o[jn][1] * inv);
      w.y = pack2bf(o[jn][2] * inv, o[jn][3] * inv);
      *(uint2*)(so + l15 * 64 + jn * 16 + l4 * 4) = w;
    }
  }
}

extern "C" void kernel_launch(void* const* d_in, const int* in_sizes, int n_in,
                              void* d_out, int out_size, void* d_ws, size_t ws_size,
                              hipStream_t stream)
{
  const void* x_raw    = d_in[0];  // [4,2048,1024]
  const void* Wqkv_raw = d_in[1];  // [1024,3072]
  const void* bqkv_raw = d_in[2];  // [3072]
  const void* Wout_raw = d_in[3];  // [1024,1024]
  const void* bout_raw = d_in[4];  // [1024]

  char* ws = (char*)d_ws;
  int*  flag   = (int*)ws;                                  //   256 B
  bf16* xb     = (bf16*)(ws + 256);                         //  16 MiB (8192*1024)
  bf16* wqkvT  = xb + (size_t)8192 * 1024;                  //   6 MiB (3072*1024, [N][K])
  bf16* bqkvb  = wqkvT + (size_t)3072 * 1024;               //   6 KiB
  bf16* woutT  = bqkvb + 4096;                              //   2 MiB (1024*1024, [N][K])
  bf16* boutb  = woutT + (size_t)1024 * 1024;               //   2 KiB
  bf16* qkv    = boutb + 4096;                              //  48 MiB (8192*3072)
  bf16* sa     = qkv + (size_t)8192 * 3072;                 //  16 MiB (8192*1024)

  detect_kernel<<<1, 64, 0, stream>>>((const unsigned int*)x_raw, flag);

  convert_kernel<<<(8192 * 1024 / 8 + 255) / 256, 256, 0, stream>>>(x_raw, xb, 8192 * 1024 / 8, flag);
  convert_bias_qkv<<<12, 256, 0, stream>>>(bqkv_raw, bqkvb, flag);
  convert_kernel<<<1, 256, 0, stream>>>(bout_raw, boutb, 1024 / 8, flag);
  transpose_bf16<<<dim3(3072 / 32, 1024 / 32), 256, 0, stream>>>(Wqkv_raw, wqkvT, 1024, 3072, flag, 1);
  transpose_bf16<<<dim3(1024 / 32, 1024 / 32), 256, 0, stream>>>(Wout_raw, woutT, 1024, 1024, flag, 0);

  // 1) qkv = x @ W_qkv + b_qkv   (M=8192, N=3072, K=1024); Q cols pre-scaled
  gemm_mfma<<<dim3(3072 / 128, 8192 / 128), 256, 0, stream>>>(
      xb, wqkvT, bqkvb, qkv, 8192, 3072, 1024, 0, flag);
  // 2) MFMA flash attention (transposed formulation, uniform-work pairing)
  attn_mfma<<<dim3(64, 16), 256, 0, stream>>>(qkv, sa);
  // 3) out = sa @ W_out + b_out  (M=8192, N=1024, K=1024)
  gemm_mfma<<<dim3(1024 / 128, 8192 / 128), 256, 0, stream>>>(
      sa, woutT, boutb, d_out, 8192, 1024, 1024, 1, flag);
}